// Round 7
// baseline (1046.816 us; speedup 1.0000x reference)
//
#include <hip/hip_runtime.h>
#include <hip/hip_bf16.h>

typedef __attribute__((ext_vector_type(8))) short s8v;
typedef __attribute__((ext_vector_type(4))) float f4v;
typedef unsigned short ushort;
typedef unsigned int uint;

union V8 { s8v v; short s[8]; };

__device__ __forceinline__ short f2bf(float v){
    union { __hip_bfloat16 b; short u; } x;
    x.b = __float2bfloat16(v);
    return x.u;
}
__device__ __forceinline__ float bf2f(short u){
    union { short u; __hip_bfloat16 b; } x;
    x.u = u;
    return __bfloat162float(x.b);
}
__device__ __forceinline__ void splitf(float v, short& h, short& l){
    h = f2bf(v);
    l = f2bf(v - bf2f(h));
}
__device__ __forceinline__ uint packsplit(float v){
    short h, l; splitf(v, h, l);
    return (uint)(ushort)h | ((uint)(ushort)l << 16);
}

// ---------------------------------------------------------------------------
// conv1 (CIN=3): direct conv + pool + ReLU -> NHWC interleaved-split u32.
// ---------------------------------------------------------------------------
template<int CIN, int HIN, int PH, int OCB, int SPT, int CICH, int COUT>
__global__ __launch_bounds__(SPT) void k_conv_pool_relu(
    const float* __restrict__ in, const float* __restrict__ w,
    const float* __restrict__ bias, uint* __restrict__ out)
{
    constexpr int WIN   = HIN;
    constexpr int PW    = PH;
    constexpr int WSTR  = CICH * 9 + 1;

    __shared__ float wsh[OCB * WSTR];

    const int b   = blockIdx.z;
    const int oc0 = blockIdx.y * OCB;
    const int t   = threadIdx.x;
    const int sp  = blockIdx.x * SPT + t;
    const bool active = sp < PH * PW;
    const int py = active ? (sp / PW) : 0;
    const int px = active ? (sp % PW) : 0;

    float acc[OCB][4];
#pragma unroll
    for (int j = 0; j < OCB; ++j)
        acc[j][0] = acc[j][1] = acc[j][2] = acc[j][3] = 0.f;

    const float* inb = in + (size_t)b * CIN * HIN * WIN;

    for (int c0 = 0; c0 < CIN; c0 += CICH) {
        __syncthreads();
        for (int i = t; i < OCB * CICH * 9; i += SPT) {
            int j = i / (CICH * 9);
            int r = i - j * (CICH * 9);
            wsh[j * WSTR + r] = w[((size_t)(oc0 + j) * CIN + c0) * 9 + r];
        }
        __syncthreads();

        for (int ci = 0; ci < CICH; ++ci) {
            const float* inc = inb + (size_t)(c0 + ci) * HIN * WIN
                             + (2 * py) * WIN + 2 * px;
            float patch[4][4];
#pragma unroll
            for (int r = 0; r < 4; ++r)
#pragma unroll
                for (int c = 0; c < 4; ++c)
                    patch[r][c] = inc[r * WIN + c];

#pragma unroll
            for (int j = 0; j < OCB; ++j) {
                const float* wp = &wsh[j * WSTR + ci * 9];
#pragma unroll
                for (int kh = 0; kh < 3; ++kh)
#pragma unroll
                    for (int kw = 0; kw < 3; ++kw) {
                        float wv = wp[kh * 3 + kw];
                        acc[j][0] = fmaf(patch[kh][kw],         wv, acc[j][0]);
                        acc[j][1] = fmaf(patch[kh][kw + 1],     wv, acc[j][1]);
                        acc[j][2] = fmaf(patch[kh + 1][kw],     wv, acc[j][2]);
                        acc[j][3] = fmaf(patch[kh + 1][kw + 1], wv, acc[j][3]);
                    }
            }
        }
    }

    if (active) {
        uint tmp[OCB];
#pragma unroll
        for (int j = 0; j < OCB; ++j) {
            float m = fmaxf(fmaxf(acc[j][0], acc[j][1]),
                            fmaxf(acc[j][2], acc[j][3]));
            m = fmaxf(m + bias[oc0 + j], 0.f);
            tmp[j] = packsplit(m);
        }
        uint* ob = out + ((size_t)b * PH * PW + sp) * COUT + oc0;
#pragma unroll
        for (int q = 0; q < OCB / 4; ++q)
            ((uint4*)ob)[q] = ((const uint4*)tmp)[q];
    }
}

// ---------------------------------------------------------------------------
// Conv weight split WITH K-permutation: w[n][ci*9+r] -> planes [n][r*CIN+ci].
// ---------------------------------------------------------------------------
__global__ void k_wsplit_perm(const float* __restrict__ w, ushort* __restrict__ oh,
                              ushort* __restrict__ ol, int CIN, int total)
{
    int i = blockIdx.x * 256 + threadIdx.x;
    if (i < total) {
        int K = CIN * 9;
        int n = i / K;
        int rem = i - n * K;
        int ci = rem / 9;
        int r = rem - 9 * ci;
        short h, l; splitf(w[i], h, l);
        size_t o = (size_t)n * K + r * CIN + ci;
        oh[o] = (ushort)h; ol[o] = (ushort)l;
    }
}

// Transpose+split: f32 [K][N] -> hi/lo ushort planes [n][k]. 32x32 tiles.
__global__ __launch_bounds__(256) void k_wsplitT(
    const float* __restrict__ B, ushort* __restrict__ oh, ushort* __restrict__ ol,
    int K, int N)
{
    __shared__ float tl[32][33];
    const int n0 = blockIdx.x * 32, k0 = blockIdx.y * 32;
    const int r = threadIdx.x >> 5, c = threadIdx.x & 31;
#pragma unroll
    for (int it = 0; it < 4; ++it) {
        int row = r + it * 8;
        tl[row][c] = B[(size_t)(k0 + row) * N + n0 + c];
    }
    __syncthreads();
#pragma unroll
    for (int it = 0; it < 4; ++it) {
        int a = r + it * 8;
        float v = tl[c][a];
        short h, l; splitf(v, h, l);
        size_t o = (size_t)(n0 + a) * K + k0 + c;
        oh[o] = (ushort)h; ol[o] = (ushort)l;
    }
}

// ---------------------------------------------------------------------------
// Split-bf16 MFMA GEMM v5: LDS DOUBLE-BUFFER, ONE barrier/iter.
// Order per iter: barrier -> issue loads(k+1) -> MFMA(k) -> ds_write buf^1.
// The loads' vmcnt wait lands at the trailing ds_write, AFTER the MFMAs, so
// global latency overlaps compute (the old 2-barrier shape drained vmcnt(0)
// at the pre-MFMA barrier -> latency was serial; MfmaUtil pinned at ~20%).
// LDS: unpadded k-major [oct][row][8] (frag reads = consecutive 16B, 2-way
// bank aliasing only). 48 KB total -> 3 blocks/CU.
// Tile 64(M) x 128(N), BK=32, 4 waves (wave: 32x64, 2x4 subtiles 16x16).
// MODE 0: implicit-GEMM conv, NHWC interleaved-split u32 A, K=(kh*3+kw)*CIN+ci.
// MODE 1: FC partial (grid.z K-split), A/B hi-lo ushort planes, f32 partials.
// ---------------------------------------------------------------------------
template<int MODE, int BPRE, int EPI, int LOG2CIN, int K, int KCH, int N,
         int HIN, int PPH, int PPW, int COUT, int TPI>
__global__ __launch_bounds__(256) void k_gemm5(
    const void* __restrict__ A0, const void* __restrict__ A1,
    const void* __restrict__ B0, const void* __restrict__ B1,
    const float* __restrict__ bias, void* __restrict__ O0, void* __restrict__ O1)
{
    constexpr int CIN = 1 << LOG2CIN;
    constexpr int HH  = HIN * HIN;

    // [buf][plane][oct*ROWS*8 + row*8]
    __shared__ short As[2][2][4 * 64 * 8];
    __shared__ short Bs[2][2][4 * 128 * 8];

    const int t    = threadIdx.x;
    const int lane = t & 63;
    const int wave = t >> 6;
    const int n0   = blockIdx.y * 128;
    const int sArow = t & 63, sAoct = t >> 6;
    const int sBrow = t & 127, sBo = t >> 7;

    const uint*   ArI = nullptr;   // NHWC base at (b, y0, x0, 0)
    const ushort* Ahg = nullptr;
    const ushort* Alg = nullptr;
    int b = 0, ptile = 0, kbeg = 0, kend = K;

    if (MODE == 0) {
        b = blockIdx.x / TPI;
        ptile = blockIdx.x - b * TPI;
        int pl = ptile * 16 + (sArow >> 2);
        int quad = sArow & 3;
        int py = 0, px = 0;
        if (pl < PPH * PPW) { py = pl / PPW; px = pl - py * PPW; }
        ArI = (const uint*)A0
            + ((size_t)b * HH + (size_t)(2 * py + (quad >> 1)) * HIN
               + (2 * px + (quad & 1))) * CIN;
    } else {
        int arow = blockIdx.x * 64 + sArow;
        Ahg = (const ushort*)A0 + (size_t)arow * K;
        Alg = (const ushort*)A1 + (size_t)arow * K;
        kbeg = blockIdx.z * KCH;
        kend = kbeg + KCH;
    }

    // ---- load / store helpers ----
    auto pfA = [&](int kkx, V8& ha, V8& la) {
        const int kb = kkx + sAoct * 8;
        if (MODE == 0) {
            const int r  = kb >> LOG2CIN;
            const int cb = kb & (CIN - 1);
            const int rh = (r * 11) >> 5;       // r/3 for r<9
            const int rw = r - 3 * rh;
            const uint* g = ArI + (rh * HIN + rw) * CIN + cb;  // 32B contiguous
            uint4 v0 = *(const uint4*)g;
            uint4 v1 = *(const uint4*)(g + 4);
            uint vv[8] = {v0.x, v0.y, v0.z, v0.w, v1.x, v1.y, v1.z, v1.w};
#pragma unroll
            for (int j = 0; j < 8; ++j) {
                ha.s[j] = (short)(vv[j] & 0xffffu);
                la.s[j] = (short)(vv[j] >> 16);
            }
        } else {
            ha.v = *(const s8v*)(Ahg + kb);
            la.v = *(const s8v*)(Alg + kb);
        }
    };
    auto pfB = [&](int kkx, V8* hb, V8* lb) {
#pragma unroll
        for (int q = 0; q < 2; ++q) {
            const int o = sBo + 2 * q;
            const int kb = kkx + o * 8;
            if (BPRE) {
                hb[q].v = *(const s8v*)((const ushort*)B0 + (size_t)(n0 + sBrow) * K + kb);
                lb[q].v = *(const s8v*)((const ushort*)B1 + (size_t)(n0 + sBrow) * K + kb);
            } else if (MODE == 0) {
                const int r  = kb >> LOG2CIN;
                const int cb = kb & (CIN - 1);
                const float* bp = (const float*)B0
                    + (size_t)(n0 + sBrow) * K + (size_t)cb * 9 + r;
#pragma unroll
                for (int j = 0; j < 8; ++j)
                    splitf(bp[9 * j], hb[q].s[j], lb[q].s[j]);
            } else {
                const float* bp = (const float*)B0 + (size_t)kb * N + n0 + sBrow;
#pragma unroll
                for (int j = 0; j < 8; ++j)
                    splitf(bp[(size_t)j * N], hb[q].s[j], lb[q].s[j]);
            }
        }
    };
    auto stAB = [&](int buf, const V8& ha, const V8& la, const V8* hb, const V8* lb) {
        *(s8v*)&As[buf][0][(sAoct * 64 + sArow) * 8] = ha.v;
        *(s8v*)&As[buf][1][(sAoct * 64 + sArow) * 8] = la.v;
#pragma unroll
        for (int q = 0; q < 2; ++q) {
            const int o = sBo + 2 * q;
            *(s8v*)&Bs[buf][0][(o * 128 + sBrow) * 8] = hb[q].v;
            *(s8v*)&Bs[buf][1][(o * 128 + sBrow) * 8] = lb[q].v;
        }
    };

    f4v acc[2][4];
    const f4v z4 = {0.f, 0.f, 0.f, 0.f};
#pragma unroll
    for (int i = 0; i < 2; ++i)
#pragma unroll
        for (int j = 0; j < 4; ++j) acc[i][j] = z4;

    V8 pAh, pAl, pBh[2], pBl[2];
    pfA(kbeg, pAh, pAl);
    pfB(kbeg, pBh, pBl);
    stAB(0, pAh, pAl, pBh, pBl);

    const int fm  = lane & 15;
    const int fo  = lane >> 4;                 // k-octet of this lane's frag
    const int amr = (wave & 1) * 32 + fm;      // A row base
    const int bnr = (wave >> 1) * 64 + fm;     // B row base

    int buf = 0;
    for (int kk = kbeg; kk < kend; kk += 32) {
        __syncthreads();                       // tile[buf] visible; vmcnt empty
        const bool more = (kk + 32 < kend);
        if (more) {                            // issue next tile's global loads
            pfA(kk + 32, pAh, pAl);            // -> overlap the MFMA phase
            pfB(kk + 32, pBh, pBl);
        }

        s8v a_h[2], a_l[2], b_h[4], b_l[4];
#pragma unroll
        for (int i = 0; i < 2; ++i) {
            a_h[i] = *(const s8v*)&As[buf][0][(fo * 64 + amr + i * 16) * 8];
            a_l[i] = *(const s8v*)&As[buf][1][(fo * 64 + amr + i * 16) * 8];
        }
#pragma unroll
        for (int j = 0; j < 4; ++j) {
            b_h[j] = *(const s8v*)&Bs[buf][0][(fo * 128 + bnr + j * 16) * 8];
            b_l[j] = *(const s8v*)&Bs[buf][1][(fo * 128 + bnr + j * 16) * 8];
        }
#define MF(a_, b_, c_) c_ = __builtin_amdgcn_mfma_f32_16x16x32_bf16(a_, b_, c_, 0, 0, 0)
#pragma unroll
        for (int i = 0; i < 2; ++i)
#pragma unroll
            for (int j = 0; j < 4; ++j) {
                MF(a_h[i], b_h[j], acc[i][j]);
                MF(a_h[i], b_l[j], acc[i][j]);
                MF(a_l[i], b_h[j], acc[i][j]);
            }
#undef MF
        if (more)
            stAB(buf ^ 1, pAh, pAl, pBh, pBl); // vmcnt wait lands HERE
        buf ^= 1;
    }

    if (MODE == 0) {
        const int PP = PPH * PPW;
#pragma unroll
        for (int i = 0; i < 2; ++i)
#pragma unroll
            for (int j = 0; j < 4; ++j) {
                int p  = ptile * 16 + (wave & 1) * 8 + i * 4 + (lane >> 4);
                int oc = n0 + (wave >> 1) * 64 + j * 16 + (lane & 15);
                if (p < PP) {
                    f4v v = acc[i][j];
                    float m = fmaxf(fmaxf(v.x, v.y), fmaxf(v.z, v.w));
                    m = fmaxf(m + bias[oc], 0.f);
                    if (EPI == 0) {
                        ((uint*)O0)[((size_t)b * PP + p) * COUT + oc] = packsplit(m);
                    } else {
                        size_t o = (size_t)(b * COUT + oc) * PP + p;
                        short h, l; splitf(m, h, l);
                        ((ushort*)O0)[o] = (ushort)h;
                        ((ushort*)O1)[o] = (ushort)l;
                    }
                }
            }
    } else {
        float* P = (float*)O0 + (size_t)blockIdx.z * 128 * N;
#pragma unroll
        for (int i = 0; i < 2; ++i)
#pragma unroll
            for (int j = 0; j < 4; ++j) {
                int n = n0 + (wave >> 1) * 64 + j * 16 + (lane & 15);
                int mb = blockIdx.x * 64 + (wave & 1) * 32 + i * 16 + (lane >> 4) * 4;
                f4v v = acc[i][j];
                P[(size_t)(mb + 0) * N + n] = v.x;
                P[(size_t)(mb + 1) * N + n] = v.y;
                P[(size_t)(mb + 2) * N + n] = v.z;
                P[(size_t)(mb + 3) * N + n] = v.w;
            }
    }
}

// FC partial-sum epilogue: sum KS partials + bias + tanh; EFMT 1: split planes,
// EFMT 2: f32.
template<int EFMT>
__global__ void k_fc_epi2(const float* __restrict__ P, const float* __restrict__ bias,
                          ushort* __restrict__ oh, ushort* __restrict__ ol,
                          float* __restrict__ of, int MN, int N, int KS)
{
    int i = blockIdx.x * 256 + threadIdx.x;
    if (i >= MN) return;
    float s = 0.f;
    for (int z = 0; z < KS; ++z) s += P[(size_t)z * MN + i];
    s = tanhf(s + bias[i % N]);
    if (EFMT == 1) {
        short h, l; splitf(s, h, l);
        oh[i] = (ushort)h; ol[i] = (ushort)l;
    } else {
        of[i] = s;
    }
}

// FC3: (128x2048) x (2048x62) f32 vector, K-split partials.
__global__ __launch_bounds__(64) void k_fc3_part(
    const float* __restrict__ A, const float* __restrict__ B,
    float* __restrict__ P, int K, int N, int KS)
{
    const int m = blockIdx.x, kz = blockIdx.y;
    const int n = threadIdx.x;
    const int kchunk = K / KS;
    if (n < N) {
        float acc = 0.f;
        const float* Am = A + (size_t)m * K;
        const int ke = (kz + 1) * kchunk;
        for (int k = kz * kchunk; k < ke; ++k)
            acc = fmaf(Am[k], B[(size_t)k * N + n], acc);
        P[((size_t)kz * 128 + m) * N + n] = acc;
    }
}

__global__ void k_fc_epi(const float* __restrict__ P, const float* __restrict__ bias,
                         float* __restrict__ out, int MN, int N, int KS)
{
    int i = blockIdx.x * 256 + threadIdx.x;
    if (i >= MN) return;
    float s = 0.f;
    for (int z = 0; z < KS; ++z) s += P[(size_t)z * MN + i];
    out[i] = s + bias[i % N];
}

// Per-batch DMP segment prep. 1x128, thread = batch.
__global__ void k_traj_start(const float* __restrict__ p, const float* __restrict__ td,
                             float* __restrict__ starts, float* __restrict__ sa,
                             int* __restrict__ sidx)
{
    int b = threadIdx.x;
    const float* pb = p + b * 62;
    float cx = pb[0], cy = pb[1];
    for (int s = 0; s < 20; ++s) {
        float f  = pb[2 + 3 * s];
        float a0 = pb[3 + 3 * s];
        float a1 = pb[4 + 3 * s];
        int idx = (int)fminf(fmaxf(rintf(f), 0.f), 999.f);
        int bs = b * 20 + s;
        sidx[bs] = idx;
        sa[bs * 2 + 0] = a0;
        sa[bs * 2 + 1] = a1;
        starts[bs * 2 + 0] = cx;
        starts[bs * 2 + 1] = cy;
        cx += td[((size_t)idx * 200 + 199) * 2 + 0] * a0;
        cy += td[((size_t)idx * 200 + 199) * 2 + 1] * a1;
    }
}

__global__ void k_traj_main(const float* __restrict__ td, const float* __restrict__ starts,
                            const float* __restrict__ sa, const int* __restrict__ sidx,
                            float* __restrict__ out)
{
    int bs = blockIdx.x;
    int idx = sidx[bs];
    float a0 = sa[bs * 2 + 0], a1 = sa[bs * 2 + 1];
    float s0 = starts[bs * 2 + 0], s1 = starts[bs * 2 + 1];
    const float* row = td + (size_t)idx * 400;
    float* o = out + (size_t)bs * 400;
    for (int e = threadIdx.x; e < 400; e += blockDim.x) {
        float v = row[e];
        o[e] = (e & 1) ? fmaf(v, a1, s1) : fmaf(v, a0, s0);
    }
}

// ---------------------------------------------------------------------------
template<int BPRE>
static void run_all(void* const* d_in, float* out, char* ws, hipStream_t stream)
{
    const float* x   = (const float*)d_in[0];
    const float* w1  = (const float*)d_in[1];
    const float* b1  = (const float*)d_in[2];
    const float* w2  = (const float*)d_in[3];
    const float* b2  = (const float*)d_in[4];
    const float* w3  = (const float*)d_in[5];
    const float* b3  = (const float*)d_in[6];
    const float* w4  = (const float*)d_in[7];
    const float* b4  = (const float*)d_in[8];
    const float* fw1 = (const float*)d_in[9];
    const float* fb1 = (const float*)d_in[10];
    const float* fw2 = (const float*)d_in[11];
    const float* fb2 = (const float*)d_in[12];
    const float* fw3 = (const float*)d_in[13];
    const float* fb3 = (const float*)d_in[14];
    const float* td  = (const float*)d_in[15];

    // ---- workspace layout (bytes), all conv activations NHWC ----
    uint*   h1   = (uint*)ws;                          // [0, 78,675,968)
    uint*   h2   = (uint*)(ws + 78675968ull);          // 34,668,544
    uint*   h3   = (uint*)ws;                          // [0, 13,107,200)
    ushort* fw1h = (ushort*)(ws + 13107200ull);        // 33,554,432
    ushort* fw1l = (ushort*)(ws + 46661632ull);        // 33,554,432
    ushort* h4h  = (ushort*)(ws + 80216064ull);        // 2,097,152 (NCHW planes)
    ushort* h4l  = (ushort*)(ws + 82313216ull);        // 2,097,152
    ushort* fw2h = (ushort*)(ws + 84410368ull);        // 8,388,608
    ushort* fw2l = (ushort*)(ws + 92798976ull);        // 8,388,608
    float*  part = (float*)(ws + 101187584ull);        // 8,388,608
    ushort* a1h  = (ushort*)(ws + 109576192ull);       // 524,288
    ushort* a1l  = (ushort*)(ws + 110100480ull);       // 524,288
    float*  a2   = (float*)(ws + 110624768ull);        // 1,048,576
    float*  p    = (float*)(ws + 111673344ull);
    float*  starts = (float*)(ws + 111705088ull);
    float*  sa   = (float*)(ws + 111725568ull);
    int*    sidx = (int*)(ws + 111746048ull);
    ushort* w2h = (ushort*)(ws + 113344512ull);
    ushort* w2l = (ushort*)(ws + 113491968ull);
    ushort* w3h = (ushort*)(ws + 113639424ull);
    ushort* w3l = (ushort*)(ws + 114229248ull);
    ushort* w4h = (ushort*)(ws + 114819072ull);
    ushort* w4l = (ushort*)(ws + 117178368ull);        // end 119,537,664

    if (BPRE) {   // permuted split: [n][ci*9+r] -> [n][r*CIN+ci]
        k_wsplit_perm<<<(73728 + 255) / 256, 256, 0, stream>>>(w2, w2h, w2l, 64, 73728);
        k_wsplit_perm<<<(294912 + 255) / 256, 256, 0, stream>>>(w3, w3h, w3l, 128, 294912);
        k_wsplit_perm<<<(1179648 + 255) / 256, 256, 0, stream>>>(w4, w4h, w4l, 256, 1179648);
    }

    // conv1: 3->64, 100 -> pool 49 (direct, NHWC out)
    k_conv_pool_relu<3, 100, 49, 16, 256, 3, 64>
        <<<dim3(10, 4, 128), 256, 0, stream>>>(x, w1, b1, h1);

    // conv2: 64->128, K=576, pooled 23x23 (34 M-tiles/img), N=128
    k_gemm5<0, BPRE, 0, 6, 576, 576, 128, 49, 23, 23, 128, 34>
        <<<dim3(34 * 128, 1), 256, 0, stream>>>(
            h1, nullptr, BPRE ? (const void*)w2h : (const void*)w2,
            BPRE ? (const void*)w2l : nullptr, b2, h2, nullptr);
    // conv3: 128->256, K=1152, pooled 10x10 (7 tiles/img), N=256
    k_gemm5<0, BPRE, 0, 7, 1152, 1152, 256, 23, 10, 10, 256, 7>
        <<<dim3(7 * 128, 2), 256, 0, stream>>>(
            h2, nullptr, BPRE ? (const void*)w3h : (const void*)w3,
            BPRE ? (const void*)w3l : nullptr, b3, h3, nullptr);

    if (BPRE) {   // h1/h2-head dead; build FC weight planes
        k_wsplitT<<<dim3(2048 / 32, 8192 / 32), 256, 0, stream>>>(fw1, fw1h, fw1l, 8192, 2048);
        k_wsplitT<<<dim3(2048 / 32, 2048 / 32), 256, 0, stream>>>(fw2, fw2h, fw2l, 2048, 2048);
    }

    // conv4: 256->512, K=2304, pooled 4x4 (1 tile/img), N=512 -> h4 NCHW planes
    k_gemm5<0, BPRE, 1, 8, 2304, 2304, 512, 10, 4, 4, 512, 1>
        <<<dim3(128, 4), 256, 0, stream>>>(
            h3, nullptr, BPRE ? (const void*)w4h : (const void*)w4,
            BPRE ? (const void*)w4l : nullptr, b4, h4h, h4l);

    // FC1: (128x8192)x(8192x2048), KS=8 partials + tanh -> a1 planes
    k_gemm5<1, BPRE, 2, 0, 8192, 1024, 2048, 1, 1, 1, 1, 1>
        <<<dim3(2, 16, 8), 256, 0, stream>>>(
            h4h, h4l, BPRE ? (const void*)fw1h : (const void*)fw1,
            BPRE ? (const void*)fw1l : nullptr, nullptr, part, nullptr);
    k_fc_epi2<1><<<(128 * 2048 + 255) / 256, 256, 0, stream>>>(
        part, fb1, a1h, a1l, nullptr, 128 * 2048, 2048, 8);
    // FC2: (128x2048)x(2048x2048), KS=8 partials + tanh -> a2 f32
    k_gemm5<1, BPRE, 2, 0, 2048, 256, 2048, 1, 1, 1, 1, 1>
        <<<dim3(2, 16, 8), 256, 0, stream>>>(
            a1h, a1l, BPRE ? (const void*)fw2h : (const void*)fw2,
            BPRE ? (const void*)fw2l : nullptr, nullptr, part, nullptr);
    k_fc_epi2<2><<<(128 * 2048 + 255) / 256, 256, 0, stream>>>(
        part, fb2, nullptr, nullptr, a2, 128 * 2048, 2048, 8);

    // FC3 (f32 vector) + trajectory composition
    k_fc3_part<<<dim3(128, 4), 64, 0, stream>>>(a2, fw3, part, 2048, 62, 4);
    k_fc_epi<<<(128 * 62 + 255) / 256, 256, 0, stream>>>(
        part, fb3, p, 128 * 62, 62, 4);
    k_traj_start<<<1, 128, 0, stream>>>(p, td, starts, sa, sidx);
    k_traj_main<<<2560, 256, 0, stream>>>(td, starts, sa, sidx, out);
}

extern "C" void kernel_launch(void* const* d_in, const int* in_sizes, int n_in,
                              void* d_out, int out_size, void* d_ws, size_t ws_size,
                              hipStream_t stream)
{
    (void)in_sizes; (void)n_in; (void)out_size;
    if (ws_size >= 119537664ull)
        run_all<1>(d_in, (float*)d_out, (char*)d_ws, stream);
    else
        run_all<0>(d_in, (float*)d_out, (char*)d_ws, stream);
}